// Round 9
// baseline (1782.824 us; speedup 1.0000x reference)
//
#include <hip/hip_runtime.h>

#define EPSN 1e-6f
#define EPSM 1e-5f

typedef __fp16 h2v __attribute__((ext_vector_type(2)));
typedef __fp16 f16x4 __attribute__((ext_vector_type(4)));
typedef float f32x4 __attribute__((ext_vector_type(4)));

// legacy mai-insts spelling; present on gfx908..gfx950 (aux-target builtin in
// host pass: usable, but __has_builtin reports false there -- no guard).
#define MFMA16(a, b, c) __builtin_amdgcn_mfma_f32_16x16x16f16((a), (b), (c), 0, 0, 0)

__device__ __forceinline__ unsigned pkh2(float a, float b) {
    union { h2v h; unsigned u; } v;
    v.h = __builtin_amdgcn_cvt_pkrtz(a, b);
    return v.u;
}

__device__ __forceinline__ float dot2f(unsigned a, unsigned b, float c) {
    union { unsigned u; h2v h; } ua, ub;
    ua.u = a; ub.u = b;
#if __has_builtin(__builtin_amdgcn_fdot2)
    return __builtin_amdgcn_fdot2(ua.h, ub.h, c, false);
#else
    return fmaf((float)ua.h.x, (float)ub.h.x,
                fmaf((float)ua.h.y, (float)ub.h.y, c));
#endif
}

// ---------------- inv L2-norm over channel dim (c=256) ----------------
__global__ __launch_bounds__(256) void invnorm_k(const float* __restrict__ f,
                                                 float* __restrict__ inv)
{
    int pbase = blockIdx.x * 64;
    int pp = threadIdx.x & 63;
    int cc = threadIdx.x >> 6;
    int pos = pbase + pp;
    int b = pos >> 10, ij = pos & 1023;
    const float* fp = f + (size_t)(b * 256) * 1024 + ij;
    float s = 0.f;
    #pragma unroll 8
    for (int k = 0; k < 64; ++k) {
        float v = fp[(size_t)(cc * 64 + k) * 1024];
        s += v * v;
    }
    __shared__ float red[4][64];
    red[cc][pp] = s;
    __syncthreads();
    if (cc == 0) {
        float t = red[0][pp] + red[1][pp] + red[2][pp] + red[3][pp];
        inv[pos] = rsqrtf(t + EPSN);
    }
}

// ---------------- correlation GEMM + relu + softsign (fp32 - precision critical) ----
__global__ __launch_bounds__(256) void corr_k(const float* __restrict__ fa,
                                              const float* __restrict__ fb,
                                              const float* __restrict__ invA,
                                              const float* __restrict__ invB,
                                              float* __restrict__ corr)
{
    __shared__ float As[16][68];
    __shared__ float Bs[16][68];
    int b = blockIdx.z;
    int i0 = blockIdx.y * 64, j0 = blockIdx.x * 64;
    int tid = threadIdx.x;
    int tx = tid & 15, ty = tid >> 4;
    const float* fab = fa + (size_t)b * 256 * 1024;
    const float* fbb = fb + (size_t)b * 256 * 1024;
    const float* ia = invA + b * 1024 + i0;
    const float* ib = invB + b * 1024 + j0;
    float acc[4][4] = {};
    for (int kc = 0; kc < 256; kc += 16) {
        #pragma unroll
        for (int l = 0; l < 4; ++l) {
            int idx = tid + l * 256;
            int r = idx >> 6, cix = idx & 63;
            As[r][cix] = fab[(size_t)(kc + r) * 1024 + i0 + cix] * ia[cix];
            Bs[r][cix] = fbb[(size_t)(kc + r) * 1024 + j0 + cix] * ib[cix];
        }
        __syncthreads();
        #pragma unroll
        for (int k = 0; k < 16; ++k) {
            float4 av = *(const float4*)&As[k][ty * 4];
            float4 bv = *(const float4*)&Bs[k][tx * 4];
            float a[4] = {av.x, av.y, av.z, av.w};
            float bq[4] = {bv.x, bv.y, bv.z, bv.w};
            #pragma unroll
            for (int ii = 0; ii < 4; ++ii)
                #pragma unroll
                for (int jj = 0; jj < 4; ++jj)
                    acc[ii][jj] += a[ii] * bq[jj];
        }
        __syncthreads();
    }
    float* cb = corr + ((size_t)b << 20);
    #pragma unroll
    for (int ii = 0; ii < 4; ++ii) {
        float4 o; float v;
        v = fmaxf(acc[ii][0], 0.f); o.x = v * rsqrtf(v * v + EPSN);
        v = fmaxf(acc[ii][1], 0.f); o.y = v * rsqrtf(v * v + EPSN);
        v = fmaxf(acc[ii][2], 0.f); o.z = v * rsqrtf(v * v + EPSN);
        v = fmaxf(acc[ii][3], 0.f); o.w = v * rsqrtf(v * v + EPSN);
        *(float4*)&cb[(size_t)(i0 + ty * 4 + ii) * 1024 + j0 + tx * 4] = o;
    }
}

// ---------------- mutual matching ----------------
__global__ __launch_bounds__(256) void rowmax_k(const float* __restrict__ c,
                                                float* __restrict__ maxR)
{
    int b = blockIdx.y, i = blockIdx.x, tid = threadIdx.x;
    const float* row = c + ((size_t)b << 20) + ((size_t)i << 10);
    float m = fmaxf(fmaxf(row[tid], row[tid + 256]), fmaxf(row[tid + 512], row[tid + 768]));
    #pragma unroll
    for (int off = 32; off; off >>= 1) m = fmaxf(m, __shfl_down(m, off, 64));
    __shared__ float sred[4];
    if ((tid & 63) == 0) sred[tid >> 6] = m;
    __syncthreads();
    if (tid == 0)
        maxR[b * 1024 + i] = fmaxf(fmaxf(sred[0], sred[1]), fmaxf(sred[2], sred[3]));
}

__global__ __launch_bounds__(256) void colmax_k(const float* __restrict__ c,
                                                float* __restrict__ maxC)
{
    int j = blockIdx.x * 256 + threadIdx.x;
    int r0 = blockIdx.y * 128;
    int b = blockIdx.z;
    const float* cb = c + ((size_t)b << 20);
    float m = 0.f;
    for (int r = 0; r < 128; ++r) m = fmaxf(m, cb[(size_t)(r0 + r) * 1024 + j]);
    atomicMax((int*)&maxC[b * 1024 + j], __float_as_int(m));
}

__global__ __launch_bounds__(256) void mmapply_k(float* __restrict__ c,
                                                 const float* __restrict__ maxR,
                                                 const float* __restrict__ maxC)
{
    int e4 = blockIdx.x * 256 + threadIdx.x;
    int e = e4 * 4;
    int b = e >> 20, i = (e >> 10) & 1023, j0 = e & 1023;
    float4 v = ((float4*)c)[e4];
    float ra = 1.f / (maxR[b * 1024 + i] + EPSM);
    float4 mb = ((const float4*)maxC)[(b * 1024 + j0) >> 2];
    float4 o;
    o.x = v.x * v.x * v.x * ra / (mb.x + EPSM);
    o.y = v.y * v.y * v.y * ra / (mb.y + EPSM);
    o.z = v.z * v.z * v.z * ra / (mb.z + EPSM);
    o.w = v.w * v.w * v.w * ra / (mb.w + EPSM);
    ((float4*)c)[e4] = o;
}

// ---------------- f32 weight pack (layer 1): [CO][CI][81] -> [CI][27][WS] ------
template <int CI, int CO>
__global__ void packw_k(const float* __restrict__ w, float* __restrict__ dst, int perm)
{
    constexpr int WS = (3 * CO + 3) & ~3;
    int idx = blockIdx.x * 256 + threadIdx.x;
    if (idx >= CI * 27 * WS) return;
    int ci = idx / (27 * WS);
    int rem = idx - ci * 27 * WS;
    int d123 = rem / WS;
    int slot = rem - d123 * WS;
    float v = 0.f;
    if (slot < 3 * CO) {
        int d4 = slot / CO, co = slot - d4 * CO;
        int t = d123 * 3 + d4;
        int d1 = t / 27, r2 = t % 27;
        int d2 = r2 / 9, r3 = r2 % 9;
        int d3 = r3 / 3, dd4 = r3 % 3;
        int st = perm ? (d3 * 27 + dd4 * 9 + d1 * 3 + d2) : t;
        v = w[(co * CI + ci) * 81 + st];
    }
    dst[idx] = v;
}

// ---------------- mfma weight pack (layer 2): [10][10][81] -> [81][co16][k16] f16
__global__ void packwm_k(const float* __restrict__ w, unsigned short* __restrict__ dst,
                         int perm)
{
    int idx = blockIdx.x * 256 + threadIdx.x;   // 81*256 = 20736
    if (idx >= 20736) return;
    int tap = idx >> 8;
    int co  = (idx >> 4) & 15;
    int k   = idx & 15;
    float v = 0.f;
    if (co < 10 && k < 10) {
        int d1 = tap / 27, r2 = tap % 27;
        int d2 = r2 / 9, r3 = r2 % 9;
        int d3 = r3 / 3, d4 = r3 % 3;
        int st = perm ? (d3 * 27 + d4 * 9 + d1 * 3 + d2) : tap;
        v = w[(co * 10 + k) * 81 + st];
    }
    union { __fp16 h; unsigned short u; } cv;
    cv.h = (__fp16)v;
    dst[idx] = cv.u;
}

// ---------------- f16-pair weight pack (layer 3): [CO][2*CIP][81] -> [CIP][27][WS]
template <int CIP, int CO>
__global__ void packw2_k(const float* __restrict__ w, unsigned* __restrict__ dst, int perm)
{
    constexpr int WS = (3 * CO + 3) & ~3;
    int idx = blockIdx.x * 256 + threadIdx.x;
    if (idx >= CIP * 27 * WS) return;
    int pp = idx / (27 * WS);
    int rem = idx - pp * 27 * WS;
    int d123 = rem / WS;
    int slot = rem - d123 * WS;
    unsigned v = 0u;
    if (slot < 3 * CO) {
        int d4 = slot / CO, co = slot - d4 * CO;
        int t = d123 * 3 + d4;
        int d1 = t / 27, r2 = t % 27;
        int d2 = r2 / 9, r3 = r2 % 9;
        int d3 = r3 / 3, dd4 = r3 % 3;
        int st = perm ? (d3 * 27 + dd4 * 9 + d1 * 3 + d2) : t;
        float f0 = w[(co * 2 * CIP + 2 * pp) * 81 + st];
        float f1 = w[(co * 2 * CIP + 2 * pp + 1) * 81 + st];
        v = pkh2(f0, f1);
    }
    dst[idx] = v;
}

// ---------------- f32 4D conv (layer 1, CI=1), packed-f16-pair output ----------
template <int CI, int CO, bool ADD, bool PACK>
__global__ __launch_bounds__(256, 4) void conv4d_k(const float* __restrict__ x,
                                                   const float* __restrict__ wp,
                                                   const float* __restrict__ bias,
                                                   float* __restrict__ y)
{
    constexpr int WS = (3 * CO + 3) & ~3;
    constexpr int NW4 = WS / 4;
    constexpr int SLAB = 34 * 35;
    __shared__ float tile[3 * SLAB];

    int tid = threadIdx.x;
    int f1 = blockIdx.x >> 5, f2 = blockIdx.x & 31;
    int q = tid & 7, yy = tid >> 3;
    int x0 = q << 2;

    for (int e = tid; e < 3 * SLAB; e += 256) tile[e] = 0.f;

    float acc[CO][4];
    #pragma unroll
    for (int co = 0; co < CO; ++co) {
        float bv = bias[co];
        acc[co][0] = bv; acc[co][1] = bv; acc[co][2] = bv; acc[co][3] = bv;
    }

    float bufA[WS], bufB[WS];

#define TAP(U, WB, WN, PF) do {                                               \
        constexpr int u_ = (U);                                               \
        const float* rowb_ = &tile[(u_/3)*SLAB + (yy + u_%3)*35 + x0];        \
        float xs_[6];                                                         \
        _Pragma("unroll") for (int j = 0; j < 6; ++j) xs_[j] = rowb_[j];      \
        if (PF) {                                                             \
            _Pragma("unroll") for (int k = 0; k < NW4; ++k)                   \
                *(float4*)&WN[k*4] =                                          \
                    ((const float4*)(wphase + (u_+1)*WS))[k];                 \
        }                                                                     \
        _Pragma("unroll") for (int d4 = 0; d4 < 3; ++d4)                      \
        _Pragma("unroll") for (int co = 0; co < CO; ++co) {                   \
            float wf_ = WB[d4*CO + co];                                       \
            _Pragma("unroll") for (int p = 0; p < 4; ++p)                     \
                acc[co][p] = fmaf(xs_[p + d4], wf_, acc[co][p]);              \
        }                                                                     \
    } while (0)

    #pragma unroll 1
    for (int ci = 0; ci < CI; ++ci) {
        const float* wci = wp + ci * 27 * WS;
        #pragma unroll 1
        for (int d1 = 0; d1 < 3; ++d1) {
            int g1 = f1 + d1 - 1;
            bool g1ok = (unsigned)g1 < 32u;
            const float* wphase = wci + d1 * 9 * WS;
            __syncthreads();
            #pragma unroll
            for (int k = 0; k < NW4; ++k)
                *(float4*)&bufA[k*4] = ((const float4*)wphase)[k];
            #pragma unroll
            for (int it = 0; it < 3; ++it) {
                int e = tid + it * 256;
                int s2 = e >> 8, rr = (e >> 3) & 31, qq = e & 7;
                int g2 = f2 + s2 - 1;
                float4 v = {0.f, 0.f, 0.f, 0.f};
                if (g1ok & ((unsigned)g2 < 32u))
                    v = *(const float4*)&x[((size_t)ci << 20) +
                        ((size_t)((g1 << 5) + g2) << 10) + (rr << 5) + (qq << 2)];
                float* t = &tile[s2 * SLAB + (rr + 1) * 35 + 1 + (qq << 2)];
                t[0] = v.x; t[1] = v.y; t[2] = v.z; t[3] = v.w;
            }
            __syncthreads();

            TAP(0, bufA, bufB, true);
            TAP(1, bufB, bufA, true);
            TAP(2, bufA, bufB, true);
            TAP(3, bufB, bufA, true);
            TAP(4, bufA, bufB, true);
            TAP(5, bufB, bufA, true);
            TAP(6, bufA, bufB, true);
            TAP(7, bufB, bufA, true);
            TAP(8, bufA, bufB, false);
        }
    }
#undef TAP

    size_t obase = ((size_t)(f1 * 32 + f2) << 10) + yy * 32 + x0;
    if (PACK) {
        unsigned* ypu = (unsigned*)y;
        #pragma unroll
        for (int c = 0; c < CO / 2; ++c) {
            uint4 o;
            o.x = pkh2(fmaxf(acc[2*c][0], 0.f), fmaxf(acc[2*c+1][0], 0.f));
            o.y = pkh2(fmaxf(acc[2*c][1], 0.f), fmaxf(acc[2*c+1][1], 0.f));
            o.z = pkh2(fmaxf(acc[2*c][2], 0.f), fmaxf(acc[2*c+1][2], 0.f));
            o.w = pkh2(fmaxf(acc[2*c][3], 0.f), fmaxf(acc[2*c+1][3], 0.f));
            *(uint4*)&ypu[(size_t)c * 1048576 + obase] = o;
        }
    } else {
        #pragma unroll
        for (int co = 0; co < CO; ++co) {
            float4 o;
            o.x = fmaxf(acc[co][0], 0.f);
            o.y = fmaxf(acc[co][1], 0.f);
            o.z = fmaxf(acc[co][2], 0.f);
            o.w = fmaxf(acc[co][3], 0.f);
            float* yp = y + ((size_t)co << 20) + obase;
            if (ADD) {
                float4 prev = *(const float4*)yp;
                o.x += prev.x; o.y += prev.y; o.z += prev.z; o.w += prev.w;
            }
            *(float4*)yp = o;
        }
    }
}

// ---------------- MFMA 4D conv (layer 2: CI=10, CO=10) ------------------------
// Async-stage split (T14): phase d1's global loads are issued during phase
// d1-1's MFMA compute; phase body = barrier -> reg->LDS write -> issue next
// loads -> barrier -> setprio(1) MFMA cluster setprio(0).
__global__ __launch_bounds__(256, 4) void conv4dm_k(const unsigned* __restrict__ xp,
                                                    const unsigned short* __restrict__ wm,
                                                    const float* __restrict__ bias,
                                                    unsigned* __restrict__ yp)
{
    __shared__ unsigned tile[3 * 10 * 34 * 9];   // 9180 u32 = 36720 B

    int tid = threadIdx.x;
    int bx = blockIdx.x;
    int chunk  = bx & 7;          // XCD id (round-robin heuristic)
    int within = bx >> 3;
    int f1 = (chunk << 2) | (within >> 7);
    int f2 = (within >> 2) & 31;
    int q  = within & 3;

    int l  = tid & 63;
    int wv = tid >> 6;        // wave 0..3
    int sl = l & 15;          // A: co-row; B/D: spatial col
    int g  = l >> 4;          // k-group / D row-group

    for (int e = tid; e < 9180; e += 256) tile[e] = 0u;

    f32x4 bv;
    #pragma unroll
    for (int e = 0; e < 4; ++e) {
        int co = 4 * g + e;
        bv[e] = (co < 10) ? bias[co] : 0.f;
    }
    f32x4 acc0 = bv, acc1 = bv, acc2 = bv, acc3 = bv;

    int qbase = q * 8;

    // stager geometry (fixed per thread)
    bool stager = tid < 240;
    int sk = tid & 7, srg = tid >> 3;
    int sr = srg % 10, ss2 = srg / 10;
    int sc = 1 + (sk << 2);
    int sg2 = f2 + ss2 - 1;
    int sg3 = qbase + sr - 1;
    bool sok = ((unsigned)sg2 < 32u) & ((unsigned)sg3 < 32u);
    size_t sbase = (((size_t)(unsigned)sg2) << 10) + (sg3 << 5) + (sc - 1);
    unsigned* stp = &tile[((ss2 * 10 + sr) * 34 + sc) * 9];

    uint4 v0, v1, v2, v3, v4;
#define LOADP(G1) do {                                                        \
        if (stager) {                                                         \
            if (sok & ((unsigned)(G1) < 32u)) {                               \
                size_t off_ = (((size_t)(unsigned)(G1)) << 15) + sbase;       \
                v0 = *(const uint4*)&xp[off_];                                \
                v1 = *(const uint4*)&xp[off_ + 1048576];                      \
                v2 = *(const uint4*)&xp[off_ + 2097152];                      \
                v3 = *(const uint4*)&xp[off_ + 3145728];                      \
                v4 = *(const uint4*)&xp[off_ + 4194304];                      \
            } else {                                                          \
                v0 = v1 = v2 = v3 = v4 = (uint4){0u, 0u, 0u, 0u};             \
            }                                                                 \
        }                                                                     \
    } while (0)

    LOADP(f1 - 1);   // prologue: phase d1=0

    #pragma unroll 1
    for (int d1 = 0; d1 < 3; ++d1) {
        // this phase's 27 A-fragments (latency overlaps the barrier below)
        uint2 aw[27];
        #pragma unroll
        for (int t27 = 0; t27 < 27; ++t27)
            aw[t27] = *(const uint2*)&wm[((d1 * 27 + t27) << 8) + (sl << 4) + (g << 2)];

        __syncthreads();   // previous-phase tile consumers done (and zero-init)
        if (stager) {
            stp[0] = v0.x; stp[9]  = v0.y; stp[18] = v0.z; stp[27] = v0.w;
            stp[1] = v1.x; stp[10] = v1.y; stp[19] = v1.z; stp[28] = v1.w;
            stp[2] = v2.x; stp[11] = v2.y; stp[20] = v2.z; stp[29] = v2.w;
            stp[3] = v3.x; stp[12] = v3.y; stp[21] = v3.z; stp[30] = v3.w;
            stp[4] = v4.x; stp[13] = v4.y; stp[22] = v4.z; stp[31] = v4.w;
        }
        if (d1 < 2)
            LOADP(f1 + d1);   // next phase's g1 = f1 - 1 + (d1+1)
        __syncthreads();

        __builtin_amdgcn_s_setprio(1);
        int tb0 = ((wv * 2 + 0) * 34 + sl) * 9 + (g << 1);
        #pragma unroll
        for (int d2 = 0; d2 < 3; ++d2)
        #pragma unroll
        for (int d3 = 0; d3 < 3; ++d3)
        #pragma unroll
        for (int d4 = 0; d4 < 3; ++d4) {
            int t27 = d2 * 9 + d3 * 3 + d4;
            union { uint2 u; f16x4 h; } A; A.u = aw[t27];
            int tapoff = ((d2 * 10 + d3) * 34 + d4) * 9;
            const unsigned* bp = &tile[tb0 + tapoff];
            union { uint2 u; f16x4 h; } B;
            B.u.x = bp[0];           B.u.y = bp[1];
            acc0 = MFMA16(A.h, B.h, acc0);
            B.u.x = bp[16 * 9];      B.u.y = bp[16 * 9 + 1];
            acc1 = MFMA16(A.h, B.h, acc1);
            B.u.x = bp[34 * 9];      B.u.y = bp[34 * 9 + 1];
            acc2 = MFMA16(A.h, B.h, acc2);
            B.u.x = bp[50 * 9];      B.u.y = bp[50 * 9 + 1];
            acc3 = MFMA16(A.h, B.h, acc3);
        }
        __builtin_amdgcn_s_setprio(0);
    }
#undef LOADP

    // epilogue: relu + pack co-pairs into padded LDS, then dense uint4 stores.
    __syncthreads();
#define EPST(ACC, RT, CH) do {                                                \
        int row_ = (RT);                                                      \
        int col_ = (CH) * 16 + sl;                                            \
        float r0 = fmaxf((ACC)[0], 0.f), r1 = fmaxf((ACC)[1], 0.f);           \
        float r2 = fmaxf((ACC)[2], 0.f), r3 = fmaxf((ACC)[3], 0.f);           \
        if (g < 2) {                                                          \
            tile[((2*g)     * 8 + row_) * 33 + col_] = pkh2(r0, r1);          \
            tile[((2*g + 1) * 8 + row_) * 33 + col_] = pkh2(r2, r3);          \
        } else if (g == 2) {                                                  \
            tile[(4 * 8 + row_) * 33 + col_] = pkh2(r0, r1);                  \
        }                                                                     \
    } while (0)
    EPST(acc0, wv * 2 + 0, 0);
    EPST(acc1, wv * 2 + 0, 1);
    EPST(acc2, wv * 2 + 1, 0);
    EPST(acc3, wv * 2 + 1, 1);
#undef EPST
    __syncthreads();

    size_t pbase = ((size_t)((f1 << 5) + f2) << 10);
    #pragma unroll
    for (int u = tid; u < 320; u += 256) {
        int p   = u >> 6;
        int rem = u & 63;
        int row = rem >> 3;
        int cg  = rem & 7;
        const unsigned* src = &tile[(p * 8 + row) * 33 + (cg << 2)];
        uint4 v;
        v.x = src[0]; v.y = src[1]; v.z = src[2]; v.w = src[3];
        *(uint4*)&yp[(size_t)p * 1048576 + pbase +
                     ((size_t)(qbase + row) << 5) + (cg << 2)] = v;
    }
}

// ---------------- f16-pair 4D conv (layer 3): packed-pair input, dot2 ---------
// Async-stage split across the CIP*3 phases: each phase's 3 uint4 loads are
// issued during the previous phase's TAP compute.
template <int CIP, int CO, bool ADD>
__global__ __launch_bounds__(256, 4) void conv4dp_k(const unsigned* __restrict__ xp,
                                                    const unsigned* __restrict__ wp,
                                                    const float* __restrict__ bias,
                                                    float* __restrict__ y)
{
    constexpr int WS = (3 * CO + 3) & ~3;
    constexpr int NW4 = WS / 4;
    constexpr int SLAB = 34 * 35;
    __shared__ unsigned tile[3 * SLAB];

    int tid = threadIdx.x;
    int f1 = blockIdx.x >> 5, f2 = blockIdx.x & 31;
    int q = tid & 7, yy = tid >> 3;
    int x0 = q << 2;

    for (int e = tid; e < 3 * SLAB; e += 256) tile[e] = 0u;

    float acc[CO][4];
    #pragma unroll
    for (int co = 0; co < CO; ++co) {
        float bvv = bias[co];
        acc[co][0] = bvv; acc[co][1] = bvv; acc[co][2] = bvv; acc[co][3] = bvv;
    }

    unsigned bufA[WS], bufB[WS];

    // staging geometry (3 slots per thread, fixed)
    const int e0 = tid, e1 = tid + 256, e2 = tid + 512;
#define STG(I, EV)                                                            \
    const int s2_##I = (EV) >> 8, rr_##I = ((EV) >> 3) & 31, qq_##I = (EV) & 7;\
    const int g2_##I = f2 + s2_##I - 1;                                       \
    const bool ok_##I = (unsigned)g2_##I < 32u;                               \
    const size_t so_##I = (((size_t)(unsigned)g2_##I) << 10) +                \
                          (rr_##I << 5) + (qq_##I << 2);                      \
    unsigned* tp_##I = &tile[s2_##I * SLAB + (rr_##I + 1) * 35 + 1 + (qq_##I << 2)];
    STG(0, e0) STG(1, e1) STG(2, e2)
#undef STG

    uint4 sv0, sv1, sv2;
#define ISSUE(PPN, G1N) do {                                                  \
        bool g1k_ = (unsigned)(G1N) < 32u;                                    \
        const unsigned* xb_ = xp + ((size_t)(PPN) << 20) +                    \
                              (((size_t)(unsigned)(G1N)) << 15);              \
        if (g1k_ & ok_0) sv0 = *(const uint4*)&xb_[so_0];                     \
        else             sv0 = (uint4){0u, 0u, 0u, 0u};                       \
        if (g1k_ & ok_1) sv1 = *(const uint4*)&xb_[so_1];                     \
        else             sv1 = (uint4){0u, 0u, 0u, 0u};                       \
        if (g1k_ & ok_2) sv2 = *(const uint4*)&xb_[so_2];                     \
        else             sv2 = (uint4){0u, 0u, 0u, 0u};                       \
    } while (0)

    ISSUE(0, f1 - 1);   // prologue: phase (pp=0, d1=0)

#define TAPP(U, WB, WN, PF) do {                                              \
        constexpr int u_ = (U);                                               \
        const unsigned* rowb_ = &tile[(u_/3)*SLAB + (yy + u_%3)*35 + x0];     \
        unsigned xs_[6];                                                      \
        _Pragma("unroll") for (int j = 0; j < 6; ++j) xs_[j] = rowb_[j];      \
        if (PF) {                                                             \
            _Pragma("unroll") for (int k = 0; k < NW4; ++k)                   \
                *(uint4*)&WN[k*4] =                                           \
                    ((const uint4*)(wphase + (u_+1)*WS))[k];                  \
        }                                                                     \
        _Pragma("unroll") for (int d4 = 0; d4 < 3; ++d4)                      \
        _Pragma("unroll") for (int co = 0; co < CO; ++co) {                   \
            unsigned wf_ = WB[d4*CO + co];                                    \
            _Pragma("unroll") for (int p = 0; p < 4; ++p)                     \
                acc[co][p] = dot2f(xs_[p + d4], wf_, acc[co][p]);             \
        }                                                                     \
    } while (0)

    #pragma unroll 1
    for (int pp = 0; pp < CIP; ++pp) {
        const unsigned* wci = wp + pp * 27 * WS;
        #pragma unroll 1
        for (int d1 = 0; d1 < 3; ++d1) {
            const unsigned* wphase = wci + d1 * 9 * WS;
            __syncthreads();   // previous tile consumers done
            tp_0[0] = sv0.x; tp_0[1] = sv0.y; tp_0[2] = sv0.z; tp_0[3] = sv0.w;
            tp_1[0] = sv1.x; tp_1[1] = sv1.y; tp_1[2] = sv1.z; tp_1[3] = sv1.w;
            tp_2[0] = sv2.x; tp_2[1] = sv2.y; tp_2[2] = sv2.z; tp_2[3] = sv2.w;
            // issue next phase's loads
            int d1n = d1 + 1, ppn = pp;
            if (d1n == 3) { d1n = 0; ppn = pp + 1; }
            if (ppn < CIP)
                ISSUE(ppn, f1 + d1n - 1);
            // tap-0 weights
            #pragma unroll
            for (int k = 0; k < NW4; ++k)
                *(uint4*)&bufA[k*4] = ((const uint4*)wphase)[k];
            __syncthreads();

            TAPP(0, bufA, bufB, true);
            TAPP(1, bufB, bufA, true);
            TAPP(2, bufA, bufB, true);
            TAPP(3, bufB, bufA, true);
            TAPP(4, bufA, bufB, true);
            TAPP(5, bufB, bufA, true);
            TAPP(6, bufA, bufB, true);
            TAPP(7, bufB, bufA, true);
            TAPP(8, bufA, bufB, false);
        }
    }
#undef TAPP
#undef ISSUE

    size_t obase = ((size_t)(f1 * 32 + f2) << 10) + yy * 32 + x0;
    #pragma unroll
    for (int co = 0; co < CO; ++co) {
        float4 o;
        o.x = fmaxf(acc[co][0], 0.f);
        o.y = fmaxf(acc[co][1], 0.f);
        o.z = fmaxf(acc[co][2], 0.f);
        o.w = fmaxf(acc[co][3], 0.f);
        float* ypt = y + ((size_t)co << 20) + obase;
        if (ADD) {
            float4 prev = *(const float4*)ypt;
            o.x += prev.x; o.y += prev.y; o.z += prev.z; o.w += prev.w;
        }
        *(float4*)ypt = o;
    }
}

extern "C" void kernel_launch(void* const* d_in, const int* in_sizes, int n_in,
                              void* d_out, int out_size, void* d_ws, size_t ws_size,
                              hipStream_t stream)
{
    (void)in_sizes; (void)n_in; (void)out_size; (void)ws_size;
    const float* fA = (const float*)d_in[0];
    const float* fB = (const float*)d_in[1];
    const float* w1 = (const float*)d_in[2];
    const float* b1 = (const float*)d_in[3];
    const float* w2 = (const float*)d_in[4];
    const float* b2 = (const float*)d_in[5];
    const float* w3 = (const float*)d_in[6];
    const float* b3 = (const float*)d_in[7];
    float* out = (float*)d_out;
    float* ws = (float*)d_ws;

    size_t o = 0;
    float* invA = ws + o; o += 4096;
    float* invB = ws + o; o += 4096;
    float* maxR = ws + o; o += 4096;
    float* maxC = ws + o; o += 4096;
    float* pw1  = ws + o; o += 2048;                       // 2 x [1][27][32] f32
    unsigned short* wm2 = (unsigned short*)(ws + o); o += 20736;  // 2 x 20736 ushort
    unsigned* pw3 = (unsigned*)(ws + o); o += 1080;        // 2 x [5][27][4] u32
    float* corr = ws + o; o += 4194304;                    // [4][1024][1024]
    unsigned* t1p = (unsigned*)(ws + o); o += 5242880;     // [5][1M] u32 pairs
    unsigned* t2p = (unsigned*)(ws + o); o += 5242880;     // [5][1M] u32 pairs

    invnorm_k<<<64, 256, 0, stream>>>(fA, invA);
    invnorm_k<<<64, 256, 0, stream>>>(fB, invB);
    corr_k<<<dim3(16, 16, 4), 256, 0, stream>>>(fA, fB, invA, invB, corr);

    // mutual matching #1 (in place on corr)
    rowmax_k<<<dim3(1024, 4), 256, 0, stream>>>(corr, maxR);
    (void)hipMemsetAsync(maxC, 0, 4096 * sizeof(float), stream);
    colmax_k<<<dim3(4, 8, 4), 256, 0, stream>>>(corr, maxC);
    mmapply_k<<<4096, 256, 0, stream>>>(corr, maxR, maxC);

    // packed weights (A = normal, B = kernel-axis-permuted symmetric branch)
    packw_k<1, 10><<<4, 256, 0, stream>>>(w1, pw1, 0);
    packw_k<1, 10><<<4, 256, 0, stream>>>(w1, pw1 + 864, 1);
    packwm_k<<<81, 256, 0, stream>>>(w2, wm2, 0);
    packwm_k<<<81, 256, 0, stream>>>(w2, wm2 + 20736, 1);
    packw2_k<5, 1><<<3, 256, 0, stream>>>(w3, pw3, 0);
    packw2_k<5, 1><<<3, 256, 0, stream>>>(w3, pw3 + 540, 1);

    for (int b = 0; b < 4; ++b) {
        const float* xb = corr + (size_t)b * 1048576;
        float* ob = out + (size_t)b * 1048576;
        conv4d_k<1, 10, false, true><<<1024, 256, 0, stream>>>(xb, pw1, b1, (float*)t1p);
        conv4dm_k<<<4096, 256, 0, stream>>>(t1p, wm2, b2, t2p);
        conv4dp_k<5, 1, false><<<1024, 256, 0, stream>>>(t2p, pw3, b3, ob);
        conv4d_k<1, 10, false, true><<<1024, 256, 0, stream>>>(xb, pw1 + 864, b1, (float*)t1p);
        conv4dm_k<<<4096, 256, 0, stream>>>(t1p, wm2 + 20736, b2, t2p);
        conv4dp_k<5, 1, true ><<<1024, 256, 0, stream>>>(t2p, pw3 + 540, b3, ob);
    }

    // mutual matching #2 (in place on out)
    rowmax_k<<<dim3(1024, 4), 256, 0, stream>>>(out, maxR);
    (void)hipMemsetAsync(maxC, 0, 4096 * sizeof(float), stream);
    colmax_k<<<dim3(4, 8, 4), 256, 0, stream>>>(out, maxC);
    mmapply_k<<<4096, 256, 0, stream>>>(out, maxR, maxC);
}